// Round 5
// baseline (1436.486 us; speedup 1.0000x reference)
//
#include <hip/hip_runtime.h>
#include <hip/hip_bf16.h>

#define NN 100000
#define NE 300000
#define NG 4096
#define EMB 256
#define NLAYERS 5

typedef unsigned short u16;
typedef unsigned int u32;

typedef short bf16x8 __attribute__((ext_vector_type(8)));
typedef float f32x4 __attribute__((ext_vector_type(4)));

__device__ __forceinline__ float b2f(u16 u){
    union { float f; u32 i; } v; v.i = ((u32)u) << 16; return v.f;
}
__device__ __forceinline__ u16 f2b(float f){
    __hip_bfloat16 h = __float2bfloat16(f);   // RNE
    union { __hip_bfloat16 h; u16 u; } v; v.h = h; return v.u;
}

// ---------------- x embedding: h = x @ xW.T + xb  (bf16 out) ----------------
#define XNB 32
__global__ __launch_bounds__(256) void embed_x(const float* __restrict__ x,
        const float* __restrict__ W, const float* __restrict__ b,
        u16* __restrict__ h)
{
    __shared__ float sW[256][41];
    __shared__ float sx[XNB][40];
    int tid = threadIdx.x;
    for (int i = tid; i < 256*40; i += 256) sW[i/40][i%40] = W[i];
    int n0 = blockIdx.x * XNB;      // 100000 = 3125*32 exact
    for (int i = tid; i < XNB*40; i += 256) {
        int j = i/40, k = i%40;
        sx[j][k] = x[(size_t)(n0+j)*40 + k];
    }
    __syncthreads();
    float bb = b[tid];
    for (int j = 0; j < XNB; ++j) {
        float a = bb;
        #pragma unroll
        for (int k = 0; k < 40; ++k) a = fmaf(sW[tid][k], sx[j][k], a);
        h[(size_t)(n0+j)*EMB + tid] = f2b(a);
    }
}

// ---------------- W -> bf16 ----------------
__global__ void wconv(const float* __restrict__ W, u16* __restrict__ Wb, int n)
{
    int i = blockIdx.x*256 + threadIdx.x;
    if (i < n) Wb[i] = f2b(W[i]);
}

// ---------------- histograms ----------------
__global__ void hist_kernel(const int* __restrict__ row, const int* __restrict__ col,
        int* __restrict__ rcnt, int* __restrict__ ccnt, int E)
{
    int e = blockIdx.x*256 + threadIdx.x;
    if (e < E) {
        atomicAdd(&rcnt[row[e]], 1);
        atomicAdd(&ccnt[col[e]], 1);
    }
}

__global__ void deg_fin(const int* __restrict__ rcnt, float* __restrict__ dinv,
                        float* __restrict__ invdg, int N)
{
    int n = blockIdx.x*256 + threadIdx.x;
    if (n < N) {
        float d = (float)rcnt[n] + 1.0f;
        dinv[n]  = rsqrtf(d);
        invdg[n] = 1.0f/d;
    }
}

// ---------------- prefix scan (3 kernels) ----------------
__global__ void scan1(const int* __restrict__ cnt, int* __restrict__ bsum, int N)
{
    __shared__ int sh[256];
    int t = threadIdx.x, i = blockIdx.x*256 + t;
    sh[t] = (i < N) ? cnt[i] : 0;
    __syncthreads();
    for (int off = 128; off > 0; off >>= 1) {
        if (t < off) sh[t] += sh[t+off];
        __syncthreads();
    }
    if (t == 0) bsum[blockIdx.x] = sh[0];
}

__global__ __launch_bounds__(512) void scan2(const int* __restrict__ bsum,
        int* __restrict__ bbase, int* __restrict__ coff, int nb)
{
    __shared__ int a[512], b[512];
    int t = threadIdx.x;
    a[t] = (t < nb) ? bsum[t] : 0;
    __syncthreads();
    int* src = a; int* dst = b;
    for (int off = 1; off < 512; off <<= 1) {
        dst[t] = (t >= off) ? src[t-off] + src[t] : src[t];
        __syncthreads();
        int* tmp = src; src = dst; dst = tmp;
    }
    bbase[t] = t ? src[t-1] : 0;
    if (t == 0) coff[NN] = NE;
}

__global__ void scan3(const int* __restrict__ cnt, const int* __restrict__ bbase,
        int* __restrict__ coff, int N)
{
    __shared__ int a[256], b[256];
    int t = threadIdx.x, i = blockIdx.x*256 + t;
    a[t] = (i < N) ? cnt[i] : 0;
    __syncthreads();
    int* src = a; int* dst = b;
    for (int off = 1; off < 256; off <<= 1) {
        dst[t] = (t >= off) ? src[t-off] + src[t] : src[t];
        __syncthreads();
        int* tmp = src; src = dst; dst = tmp;
    }
    if (i < N) coff[i] = bbase[blockIdx.x] + (t ? src[t-1] : 0);
}

// CSR fill: per-edge streams in CSR(col) order.
// erow[p] = row, enorm[p] = dinv[row]*dinv[col], eab[p][16] = bf16 eattr (10 used)
__global__ void csr_fill(const int* __restrict__ row, const int* __restrict__ col,
        const float* __restrict__ eattr, const int* __restrict__ coff,
        const float* __restrict__ dinv, int* __restrict__ fill,
        int* __restrict__ erow, float* __restrict__ enorm,
        u16* __restrict__ eab, int E)
{
    int e = blockIdx.x*256 + threadIdx.x;
    if (e < E) {
        int c = col[e], r = row[e];
        int p = coff[c] + atomicAdd(&fill[c], 1);
        erow[p]  = r;
        enorm[p] = dinv[r] * dinv[c];
        #pragma unroll
        for (int k = 0; k < 10; ++k) eab[(size_t)p*16 + k] = f2b(eattr[(size_t)e*10 + k]);
        #pragma unroll
        for (int k = 10; k < 16; ++k) eab[(size_t)p*16 + k] = 0;
    }
}

// ---------------- MFMA GEMM: C[m][o] = sum_k A[m][k]*Wb[o][k] + bias[o] ----------------
#define BM 128
#define BK 64
__global__ __launch_bounds__(256) void gemm_mfma(const u16* __restrict__ A,
        const u16* __restrict__ Wb, const float* __restrict__ bias,
        u16* __restrict__ C, int M)
{
    __shared__ u16 As[BM*BK];   // 16B chunk idx = row*8 + (ch ^ (row&7))
    __shared__ u16 Bs[BM*BK];
    const int tid  = threadIdx.x;
    const int wid  = tid >> 6;
    const int lane = tid & 63;
    const int wr = wid >> 1, wc = wid & 1;
    const int m0 = blockIdx.x * BM;
    const int n0 = blockIdx.y * BM;
    f32x4 acc[4][4] = {};
    for (int k0 = 0; k0 < 256; k0 += BK) {
        #pragma unroll
        for (int i = 0; i < 4; ++i) {
            int L = tid + i*256;
            int rowi = L >> 3, ch = L & 7;
            int sw = ch ^ (rowi & 7);
            int gr = m0 + rowi; gr = gr < M ? gr : M-1;
            uint4 va = *reinterpret_cast<const uint4*>(&A[(size_t)gr*256 + k0 + ch*8]);
            *reinterpret_cast<uint4*>(&As[(rowi*8 + sw)*8]) = va;
            uint4 vb = *reinterpret_cast<const uint4*>(&Wb[(size_t)(n0+rowi)*256 + k0 + ch*8]);
            *reinterpret_cast<uint4*>(&Bs[(rowi*8 + sw)*8]) = vb;
        }
        __syncthreads();
        const int c = lane >> 4;
        const int rl = lane & 15;
        #pragma unroll
        for (int kt = 0; kt < 2; ++kt) {
            bf16x8 af[4], bfr[4];
            #pragma unroll
            for (int f = 0; f < 4; ++f) {
                int ra = wr*64 + f*16 + rl;
                int cha = (kt*4 + c) ^ (ra & 7);
                af[f] = *reinterpret_cast<const bf16x8*>(&As[(ra*8 + cha)*8]);
                int rb = wc*64 + f*16 + rl;
                int chb = (kt*4 + c) ^ (rb & 7);
                bfr[f] = *reinterpret_cast<const bf16x8*>(&Bs[(rb*8 + chb)*8]);
            }
            #pragma unroll
            for (int fm = 0; fm < 4; ++fm)
                #pragma unroll
                for (int fn = 0; fn < 4; ++fn)
                    acc[fm][fn] = __builtin_amdgcn_mfma_f32_16x16x32_bf16(
                        af[fm], bfr[fn], acc[fm][fn], 0, 0, 0);
        }
        __syncthreads();
    }
    const int cn = lane & 15, rq = lane >> 4;
    #pragma unroll
    for (int fn = 0; fn < 4; ++fn) {
        int n = n0 + wc*64 + fn*16 + cn;
        float bb = bias[n];
        #pragma unroll
        for (int fm = 0; fm < 4; ++fm) {
            #pragma unroll
            for (int r = 0; r < 4; ++r) {
                int m = m0 + wr*64 + fm*16 + rq*4 + r;
                if (m < M) C[(size_t)m*256 + n] = f2b(acc[fm][fn][r] + bb);
            }
        }
    }
}

// ---------------- fused gather + combine + BN-stats ----------------
// Each wave owns GFB consecutive nodes, walks their FLAT CSR edge range in
// groups of 4 (MLP=4 on the hx gather). At node boundaries (wave-uniform):
// t = h_in + acc + relu(hx+root)*invdeg -> tout (bf16); BN stats in registers.
#define GFB 4
__global__ __launch_bounds__(256) void gather_combine(const int* __restrict__ erow,
        const float* __restrict__ enorm, const u16* __restrict__ eab,
        const int* __restrict__ coff,
        const float* __restrict__ eW, const float* __restrict__ eb,
        const u16* __restrict__ h, const u16* __restrict__ hx,
        const float* __restrict__ rootv, const float* __restrict__ invdg,
        u16* __restrict__ tout, float* __restrict__ stats, int N)
{
    __shared__ float red[4][512];
    const int wid = threadIdx.x >> 6, lane = threadIdx.x & 63;
    const int f4 = lane*4;
    const int nb = (blockIdx.x*4 + wid)*GFB;
    // per-lane edge-MLP weights for features f4..f4+3
    float w[4][10], bb[4];
    #pragma unroll
    for (int j = 0; j < 4; ++j) {
        bb[j] = eb[f4+j];
        #pragma unroll
        for (int k = 0; k < 10; ++k) w[j][k] = eW[(f4+j)*10 + k];
    }
    float4 root = *reinterpret_cast<const float4*>(&rootv[f4]);
    float sacc[4] = {0,0,0,0}, s2acc[4] = {0,0,0,0};

    if (nb < N) {
        int c1 = coff[nb+1], c2 = coff[nb+2], c3 = coff[nb+3], c4 = coff[nb+4];
        int s = coff[nb], e = c4;
        int jn = 0, cend = c1;
        float acc[4] = {0,0,0,0};

        // flush node nb+jn: full combine + stats, reset acc
        #define FLUSH() do {                                                   \
            int n_ = nb + jn;                                                  \
            size_t idx_ = (size_t)n_*EMB + f4;                                 \
            uint2 hv_ = *reinterpret_cast<const uint2*>(&h[idx_]);             \
            uint2 xv_ = *reinterpret_cast<const uint2*>(&hx[idx_]);            \
            float id_ = invdg[n_];                                             \
            float hh_[4] = { b2f((u16)(hv_.x&0xffffu)), b2f((u16)(hv_.x>>16)), \
                             b2f((u16)(hv_.y&0xffffu)), b2f((u16)(hv_.y>>16)) };\
            float xx_[4] = { b2f((u16)(xv_.x&0xffffu)), b2f((u16)(xv_.x>>16)), \
                             b2f((u16)(xv_.y&0xffffu)), b2f((u16)(xv_.y>>16)) };\
            float rt_[4] = { root.x, root.y, root.z, root.w };                 \
            u16 ov_[4];                                                        \
            _Pragma("unroll")                                                  \
            for (int jj = 0; jj < 4; ++jj) {                                   \
                float rv_ = xx_[jj] + rt_[jj];                                 \
                rv_ = rv_ > 0.f ? rv_ : 0.f;                                   \
                float tv_ = hh_[jj] + acc[jj] + rv_*id_;                       \
                ov_[jj] = f2b(tv_);                                            \
                sacc[jj] += tv_; s2acc[jj] += tv_*tv_;                         \
                acc[jj] = 0.f;                                                 \
            }                                                                  \
            uint2 o_; o_.x = (u32)ov_[0] | ((u32)ov_[1]<<16);                  \
            o_.y = (u32)ov_[2] | ((u32)ov_[3]<<16);                            \
            *reinterpret_cast<uint2*>(&tout[idx_]) = o_;                       \
            ++jn; cend = (jn==1) ? c2 : (jn==2) ? c3 : c4;                     \
        } while(0)

        // consume one edge given preloaded r, nrm, hv, alo, ahi
        #define CONSUME(rr, nm, hvv, alo, ahi) do {                            \
            float hf_[4] = { b2f((u16)((hvv).x&0xffffu)), b2f((u16)((hvv).x>>16)),\
                             b2f((u16)((hvv).y&0xffffu)), b2f((u16)((hvv).y>>16)) };\
            float at_[10];                                                     \
            at_[0]=b2f((u16)((alo).x&0xffffu)); at_[1]=b2f((u16)((alo).x>>16));\
            at_[2]=b2f((u16)((alo).y&0xffffu)); at_[3]=b2f((u16)((alo).y>>16));\
            at_[4]=b2f((u16)((alo).z&0xffffu)); at_[5]=b2f((u16)((alo).z>>16));\
            at_[6]=b2f((u16)((alo).w&0xffffu)); at_[7]=b2f((u16)((alo).w>>16));\
            at_[8]=b2f((u16)((ahi).x&0xffffu)); at_[9]=b2f((u16)((ahi).x>>16));\
            _Pragma("unroll")                                                  \
            for (int jj = 0; jj < 4; ++jj) {                                   \
                float ea_ = bb[jj];                                            \
                _Pragma("unroll")                                              \
                for (int k = 0; k < 10; ++k) ea_ = fmaf(at_[k], w[jj][k], ea_);\
                float v_ = hf_[jj] + ea_;                                      \
                acc[jj] += v_ > 0.f ? v_*(nm) : 0.f;                           \
            }                                                                  \
        } while(0)

        int p = s;
        // fast path: groups of 4 edges, all loads issued before consumption
        for (; p + 4 <= e; p += 4) {
            int r0 = erow[p], r1 = erow[p+1], r2 = erow[p+2], r3 = erow[p+3];
            float n0 = enorm[p], n1 = enorm[p+1], n2 = enorm[p+2], n3 = enorm[p+3];
            uint2 h0 = *reinterpret_cast<const uint2*>(&hx[(size_t)r0*EMB + f4]);
            uint2 h1 = *reinterpret_cast<const uint2*>(&hx[(size_t)r1*EMB + f4]);
            uint2 h2 = *reinterpret_cast<const uint2*>(&hx[(size_t)r2*EMB + f4]);
            uint2 h3 = *reinterpret_cast<const uint2*>(&hx[(size_t)r3*EMB + f4]);
            uint4 a0l = *reinterpret_cast<const uint4*>(&eab[(size_t)(p+0)*16]);
            uint4 a0h = *reinterpret_cast<const uint4*>(&eab[(size_t)(p+0)*16+8]);
            uint4 a1l = *reinterpret_cast<const uint4*>(&eab[(size_t)(p+1)*16]);
            uint4 a1h = *reinterpret_cast<const uint4*>(&eab[(size_t)(p+1)*16+8]);
            uint4 a2l = *reinterpret_cast<const uint4*>(&eab[(size_t)(p+2)*16]);
            uint4 a2h = *reinterpret_cast<const uint4*>(&eab[(size_t)(p+2)*16+8]);
            uint4 a3l = *reinterpret_cast<const uint4*>(&eab[(size_t)(p+3)*16]);
            uint4 a3h = *reinterpret_cast<const uint4*>(&eab[(size_t)(p+3)*16+8]);
            while (p+0 >= cend) FLUSH();
            CONSUME(r0, n0, h0, a0l, a0h);
            while (p+1 >= cend) FLUSH();
            CONSUME(r1, n1, h1, a1l, a1h);
            while (p+2 >= cend) FLUSH();
            CONSUME(r2, n2, h2, a2l, a2h);
            while (p+3 >= cend) FLUSH();
            CONSUME(r3, n3, h3, a3l, a3h);
        }
        for (; p < e; ++p) {
            int r0 = erow[p];
            float n0 = enorm[p];
            uint2 h0 = *reinterpret_cast<const uint2*>(&hx[(size_t)r0*EMB + f4]);
            uint4 a0l = *reinterpret_cast<const uint4*>(&eab[(size_t)p*16]);
            uint4 a0h = *reinterpret_cast<const uint4*>(&eab[(size_t)p*16+8]);
            while (p >= cend) FLUSH();
            CONSUME(r0, n0, h0, a0l, a0h);
        }
        while (jn < GFB) FLUSH();   // remaining (possibly empty) nodes
        #undef FLUSH
        #undef CONSUME
    }

    // block-level stats reduction
    #pragma unroll
    for (int j = 0; j < 4; ++j) {
        red[wid][f4+j]     = sacc[j];
        red[wid][256+f4+j] = s2acc[j];
    }
    __syncthreads();
    int t = threadIdx.x;
    float a0 = red[0][t] + red[1][t] + red[2][t] + red[3][t];
    float a1 = red[0][256+t] + red[1][256+t] + red[2][256+t] + red[3][256+t];
    atomicAdd(&stats[t], a0);
    atomicAdd(&stats[256+t], a1);
}

// ---------------- BN finalize ----------------
__global__ void bn_finalize(const float* __restrict__ stats,
        const float* __restrict__ gamma, const float* __restrict__ beta,
        float* __restrict__ sc, int N)
{
    int f = threadIdx.x;
    float inv = 1.0f / (float)N;
    float mean = stats[f] * inv;
    float var  = stats[256+f] * inv - mean*mean;
    float is = rsqrtf(var + 1e-5f);
    float scale = gamma[f] * is;
    sc[f] = scale;
    sc[256+f] = fmaf(-mean, scale, beta[f]);
}

// ---------------- BN apply (+optional relu), bf16, 8 elems/thread ----------------
__global__ __launch_bounds__(256) void bn_apply(const uint4* __restrict__ t,
        uint4* __restrict__ h, const float* __restrict__ sc, int n8, int doRelu)
{
    size_t i0 = (size_t)blockIdx.x*blockDim.x + threadIdx.x;
    int f = (int)((i0*8) & 255);
    float s[8], sh[8];
    #pragma unroll
    for (int j = 0; j < 8; ++j) { s[j] = sc[f+j]; sh[j] = sc[256+f+j]; }
    size_t stride = (size_t)gridDim.x*blockDim.x;
    for (size_t i = i0; i < (size_t)n8; i += stride) {
        uint4 v = t[i];
        u32 w[4] = {v.x, v.y, v.z, v.w};
        u32 o[4];
        #pragma unroll
        for (int j = 0; j < 4; ++j) {
            float lo = b2f((u16)(w[j] & 0xffffu));
            float hi = b2f((u16)(w[j] >> 16));
            lo = fmaf(lo, s[2*j],   sh[2*j]);
            hi = fmaf(hi, s[2*j+1], sh[2*j+1]);
            if (doRelu) { lo = fmaxf(lo, 0.f); hi = fmaxf(hi, 0.f); }
            o[j] = (u32)f2b(lo) | ((u32)f2b(hi) << 16);
        }
        uint4 r; r.x = o[0]; r.y = o[1]; r.z = o[2]; r.w = o[3];
        h[i] = r;
    }
}

// ---------------- mean pool over sorted batch ----------------
__global__ __launch_bounds__(256) void pool_kernel(const u16* __restrict__ h,
        const int* __restrict__ batch, float* __restrict__ psum,
        float* __restrict__ pcnt, int N)
{
    int f = threadIdx.x;
    int n0 = blockIdx.x * 256;
    int n1 = min(n0 + 256, N);
    int cur = batch[n0];
    float acc = 0.f;
    int cnt = 0;
    for (int n = n0; n < n1; ++n) {
        int g = batch[n];
        if (g != cur) {
            atomicAdd(&psum[(size_t)cur*EMB + f], acc);
            if (f == 0) atomicAdd(&pcnt[cur], (float)cnt);
            acc = 0.f; cnt = 0; cur = g;
        }
        acc += b2f(h[(size_t)n*EMB + f]);
        ++cnt;
    }
    atomicAdd(&psum[(size_t)cur*EMB + f], acc);
    if (f == 0) atomicAdd(&pcnt[cur], (float)cnt);
}

// ---------------- fused MLP head ----------------
__global__ __launch_bounds__(128) void head_kernel(const float* __restrict__ psum,
        const float* __restrict__ pcnt,
        const float* __restrict__ p1W, const float* __restrict__ p1b,
        const float* __restrict__ p2W, const float* __restrict__ p2b,
        const float* __restrict__ p3W, const float* __restrict__ p3b,
        float* __restrict__ out)
{
    __shared__ float gs[256];
    __shared__ float h1[128];
    __shared__ float h2[128];
    __shared__ float red[2];
    int g = blockIdx.x, t = threadIdx.x;
    float invc = 1.0f / fmaxf(pcnt[g], 1.0f);
    gs[t]       = psum[(size_t)g*EMB + t] * invc;
    gs[t + 128] = psum[(size_t)g*EMB + 128 + t] * invc;
    __syncthreads();
    float a = p1b[t];
    for (int k = 0; k < 256; ++k) a = fmaf(p1W[(size_t)t*256 + k], gs[k], a);
    h1[t] = fmaxf(a, 0.f);
    __syncthreads();
    float b = p2b[t];
    for (int k = 0; k < 128; ++k) b = fmaf(p2W[(size_t)t*128 + k], h1[k], b);
    h2[t] = fmaxf(b, 0.f);
    __syncthreads();
    float r = p3W[t] * h2[t];
    for (int off = 32; off > 0; off >>= 1) r += __shfl_down(r, off);
    if ((t & 63) == 0) red[t >> 6] = r;
    __syncthreads();
    if (t == 0) out[g] = red[0] + red[1] + p3b[0];
}

extern "C" void kernel_launch(void* const* d_in, const int* in_sizes, int n_in,
                              void* d_out, int out_size, void* d_ws, size_t ws_size,
                              hipStream_t stream)
{
    const float* x     = (const float*)d_in[0];
    const int*   eidx  = (const int*)d_in[1];
    const float* eattr = (const float*)d_in[2];
    const int*   batch = (const int*)d_in[3];
    const float* xW    = (const float*)d_in[4];
    const float* xb    = (const float*)d_in[5];
    const float* eW    = (const float*)d_in[6];
    const float* eb    = (const float*)d_in[7];
    const float* gcnW  = (const float*)d_in[8];
    const float* gcnb  = (const float*)d_in[9];
    const float* rootE = (const float*)d_in[10];
    const float* bng   = (const float*)d_in[11];
    const float* bnb   = (const float*)d_in[12];
    const float* p1W   = (const float*)d_in[13];
    const float* p1b   = (const float*)d_in[14];
    const float* p2W   = (const float*)d_in[15];
    const float* p2b   = (const float*)d_in[16];
    const float* p3W   = (const float*)d_in[17];
    const float* p3b   = (const float*)d_in[18];
    float* out = (float*)d_out;

    const int* row = eidx;
    const int* col = eidx + NE;

    const size_t HSZ = (size_t)NN * EMB;            // 25.6M elements
    const int NWB = 5*EMB*EMB;                      // 327680

    // ---- ws layout ----
    char* p = (char*)d_ws;
    u16* agg = (u16*)p;            p += HSZ*2;      // holds t after gather_combine
    u16* h   = (u16*)p;            p += HSZ*2;
    u16* hx  = (u16*)p;            p += HSZ*2;
    u16* Wb  = (u16*)p;            p += (size_t)NWB*2;
    // zeroed accumulator region
    char* zbase = p;
    int* rcnt   = (int*)p;         p += (size_t)NN*4;
    int* ccnt   = (int*)p;         p += (size_t)NN*4;
    int* fill   = (int*)p;         p += (size_t)NN*4;
    float* stats= (float*)p;       p += (size_t)NLAYERS*512*4;
    float* psum = (float*)p;       p += (size_t)NG*EMB*4;
    float* pcnt = (float*)p;       p += (size_t)NG*4;
    size_t zbytes = (size_t)(p - zbase);
    float* dinv = (float*)p;       p += (size_t)NN*4;
    float* invdg= (float*)p;       p += (size_t)NN*4;
    float* bnsc = (float*)p;       p += 512*4;
    int* coff   = (int*)p;         p += (size_t)(NN+1)*4;
    int* bsum   = (int*)p;         p += 512*4;
    int* bbase  = (int*)p;         p += 512*4;
    int* erow   = (int*)p;         p += (size_t)NE*4;
    float* enorm= (float*)p;       p += (size_t)NE*4;
    u16* eab    = (u16*)p;         p += (size_t)NE*16*2;
    size_t NEED = (size_t)(p - (char*)d_ws);
    if (ws_size < NEED) return;    // fail absmax cleanly instead of faulting

    hipMemsetAsync(zbase, 0, zbytes, stream);

    const int NBS = (NN + 255)/256;

    embed_x<<<NN/XNB, 256, 0, stream>>>(x, xW, xb, h);
    wconv<<<(NWB+255)/256, 256, 0, stream>>>(gcnW, Wb, NWB);
    hist_kernel<<<(NE+255)/256, 256, 0, stream>>>(row, col, rcnt, ccnt, NE);
    deg_fin<<<NBS, 256, 0, stream>>>(rcnt, dinv, invdg, NN);
    scan1<<<NBS, 256, 0, stream>>>(ccnt, bsum, NN);
    scan2<<<1, 512, 0, stream>>>(bsum, bbase, coff, NBS);
    scan3<<<NBS, 256, 0, stream>>>(ccnt, bbase, coff, NN);
    csr_fill<<<(NE+255)/256, 256, 0, stream>>>(row, col, eattr, coff, dinv, fill,
                                               erow, enorm, eab, NE);

    for (int l = 0; l < NLAYERS; ++l) {
        const u16*   Wl = Wb + (size_t)l*EMB*EMB;
        const float* bl = gcnb + (size_t)l*EMB;
        const float* rl = rootE + (size_t)l*EMB;
        dim3 ggrid((NN + BM - 1)/BM, EMB/BM);
        gemm_mfma<<<ggrid, 256, 0, stream>>>(h, Wl, bl, hx, NN);
        gather_combine<<<(NN + 4*GFB - 1)/(4*GFB), 256, 0, stream>>>(erow, enorm,
                eab, coff, eW, eb, h, hx, rl, invdg, agg, stats + l*512, NN);
        bn_finalize<<<1, 256, 0, stream>>>(stats + l*512, bng + (size_t)l*EMB,
                                           bnb + (size_t)l*EMB, bnsc, NN);
        bn_apply<<<2048, 256, 0, stream>>>((const uint4*)agg, (uint4*)h, bnsc,
                                           (int)(HSZ/8), (l != NLAYERS-1) ? 1 : 0);
    }

    pool_kernel<<<NBS, 256, 0, stream>>>(h, batch, psum, pcnt, NN);
    head_kernel<<<NG, 128, 0, stream>>>(psum, pcnt, p1W, p1b, p2W, p2b, p3W, p3b, out);
}

// Round 6
// 1006.827 us; speedup vs baseline: 1.4267x; 1.4267x over previous
//
#include <hip/hip_runtime.h>
#include <hip/hip_bf16.h>

#define NN 100000
#define NE 300000
#define NG 4096
#define EMB 256
#define NLAYERS 5

typedef unsigned short u16;
typedef unsigned int u32;

typedef short bf16x8 __attribute__((ext_vector_type(8)));
typedef float f32x4 __attribute__((ext_vector_type(4)));

__device__ __forceinline__ float b2f(u16 u){
    union { float f; u32 i; } v; v.i = ((u32)u) << 16; return v.f;
}
__device__ __forceinline__ u16 f2b(float f){
    __hip_bfloat16 h = __float2bfloat16(f);   // RNE
    union { __hip_bfloat16 h; u16 u; } v; v.h = h; return v.u;
}

// ---------------- x embedding: t = x @ xW.T + xb  (bf16 out, raw/pre-BN) ------
#define XNB 32
__global__ __launch_bounds__(256) void embed_x(const float* __restrict__ x,
        const float* __restrict__ W, const float* __restrict__ b,
        u16* __restrict__ t)
{
    __shared__ float sW[256][41];
    __shared__ float sx[XNB][40];
    int tid = threadIdx.x;
    for (int i = tid; i < 256*40; i += 256) sW[i/40][i%40] = W[i];
    int n0 = blockIdx.x * XNB;      // 100000 = 3125*32 exact
    for (int i = tid; i < XNB*40; i += 256) {
        int j = i/40, k = i%40;
        sx[j][k] = x[(size_t)(n0+j)*40 + k];
    }
    __syncthreads();
    float bb = b[tid];
    for (int j = 0; j < XNB; ++j) {
        float a = bb;
        #pragma unroll
        for (int k = 0; k < 40; ++k) a = fmaf(sW[tid][k], sx[j][k], a);
        t[(size_t)(n0+j)*EMB + tid] = f2b(a);
    }
}

// ---------------- W -> bf16 ----------------
__global__ void wconv(const float* __restrict__ W, u16* __restrict__ Wb, int n)
{
    int i = blockIdx.x*256 + threadIdx.x;
    if (i < n) Wb[i] = f2b(W[i]);
}

// ---------------- eW transpose: eWt[k*256+f] = eW[f*10+k] ----------------
__global__ void ewt_kernel(const float* __restrict__ eW, float* __restrict__ eWt)
{
    int i = blockIdx.x*256 + threadIdx.x;
    if (i < 2560) { int f = i/10, k = i%10; eWt[k*256 + f] = eW[i]; }
}

// ---------------- histograms ----------------
__global__ void hist_kernel(const int* __restrict__ row, const int* __restrict__ col,
        int* __restrict__ rcnt, int* __restrict__ ccnt, int E)
{
    int e = blockIdx.x*256 + threadIdx.x;
    if (e < E) {
        atomicAdd(&rcnt[row[e]], 1);
        atomicAdd(&ccnt[col[e]], 1);
    }
}

__global__ void deg_fin(const int* __restrict__ rcnt, float* __restrict__ dinv,
                        float* __restrict__ invdg, int N)
{
    int n = blockIdx.x*256 + threadIdx.x;
    if (n < N) {
        float d = (float)rcnt[n] + 1.0f;
        dinv[n]  = rsqrtf(d);
        invdg[n] = 1.0f/d;
    }
}

// ---------------- prefix scan (3 kernels) ----------------
__global__ void scan1(const int* __restrict__ cnt, int* __restrict__ bsum, int N)
{
    __shared__ int sh[256];
    int t = threadIdx.x, i = blockIdx.x*256 + t;
    sh[t] = (i < N) ? cnt[i] : 0;
    __syncthreads();
    for (int off = 128; off > 0; off >>= 1) {
        if (t < off) sh[t] += sh[t+off];
        __syncthreads();
    }
    if (t == 0) bsum[blockIdx.x] = sh[0];
}

__global__ __launch_bounds__(512) void scan2(const int* __restrict__ bsum,
        int* __restrict__ bbase, int* __restrict__ coff, int nb)
{
    __shared__ int a[512], b[512];
    int t = threadIdx.x;
    a[t] = (t < nb) ? bsum[t] : 0;
    __syncthreads();
    int* src = a; int* dst = b;
    for (int off = 1; off < 512; off <<= 1) {
        dst[t] = (t >= off) ? src[t-off] + src[t] : src[t];
        __syncthreads();
        int* tmp = src; src = dst; dst = tmp;
    }
    bbase[t] = t ? src[t-1] : 0;
    if (t == 0) coff[NN] = NE;
}

__global__ void scan3(const int* __restrict__ cnt, const int* __restrict__ bbase,
        int* __restrict__ coff, int N)
{
    __shared__ int a[256], b[256];
    int t = threadIdx.x, i = blockIdx.x*256 + t;
    a[t] = (i < N) ? cnt[i] : 0;
    __syncthreads();
    int* src = a; int* dst = b;
    for (int off = 1; off < 256; off <<= 1) {
        dst[t] = (t >= off) ? src[t-off] + src[t] : src[t];
        __syncthreads();
        int* tmp = src; src = dst; dst = tmp;
    }
    if (i < N) coff[i] = bbase[blockIdx.x] + (t ? src[t-1] : 0);
}

// CSR fill: per-edge streams in CSR(col) order.
__global__ void csr_fill(const int* __restrict__ row, const int* __restrict__ col,
        const float* __restrict__ eattr, const int* __restrict__ coff,
        const float* __restrict__ dinv, int* __restrict__ fill,
        int* __restrict__ erow, float* __restrict__ enorm,
        u16* __restrict__ eab, int E)
{
    int e = blockIdx.x*256 + threadIdx.x;
    if (e < E) {
        int c = col[e], r = row[e];
        int p = coff[c] + atomicAdd(&fill[c], 1);
        erow[p]  = r;
        enorm[p] = dinv[r] * dinv[c];
        #pragma unroll
        for (int k = 0; k < 10; ++k) eab[(size_t)p*16 + k] = f2b(eattr[(size_t)e*10 + k]);
        #pragma unroll
        for (int k = 10; k < 16; ++k) eab[(size_t)p*16 + k] = 0;
    }
}

// ---------------- MFMA GEMM with fused input-BN ----------------
// C[m][o] = sum_k affine(A[m][k]) * Wb[o][k] + bias[o]
// affine (doBN=1): a -> relu(a*sc[k]+sh[k]); (doBN=0): identity.
#define BM 128
#define BK 64
__global__ __launch_bounds__(256) void gemm_mfma(const u16* __restrict__ A,
        const u16* __restrict__ Wb, const float* __restrict__ bias,
        const float* __restrict__ bnsc, int doBN,
        u16* __restrict__ C, int M)
{
    __shared__ u16 As[BM*BK];   // 16B chunk idx = row*8 + (ch ^ (row&7))
    __shared__ u16 Bs[BM*BK];
    __shared__ float scS[256], shS[256];
    const int tid  = threadIdx.x;
    if (doBN) { scS[tid] = bnsc[tid]; shS[tid] = bnsc[256+tid]; }
    const int wid  = tid >> 6;
    const int lane = tid & 63;
    const int wr = wid >> 1, wc = wid & 1;
    const int m0 = blockIdx.x * BM;
    const int n0 = blockIdx.y * BM;
    __syncthreads();
    f32x4 acc[4][4] = {};
    for (int k0 = 0; k0 < 256; k0 += BK) {
        #pragma unroll
        for (int i = 0; i < 4; ++i) {
            int L = tid + i*256;
            int rowi = L >> 3, ch = L & 7;
            int sw = ch ^ (rowi & 7);
            int gr = m0 + rowi; gr = gr < M ? gr : M-1;
            uint4 va = *reinterpret_cast<const uint4*>(&A[(size_t)gr*256 + k0 + ch*8]);
            if (doBN) {
                int kk = k0 + ch*8;
                u32 wv[4] = {va.x, va.y, va.z, va.w};
                #pragma unroll
                for (int j = 0; j < 4; ++j) {
                    float lo = b2f((u16)(wv[j] & 0xffffu));
                    float hi = b2f((u16)(wv[j] >> 16));
                    lo = fmaxf(fmaf(lo, scS[kk+2*j],   shS[kk+2*j]),   0.f);
                    hi = fmaxf(fmaf(hi, scS[kk+2*j+1], shS[kk+2*j+1]), 0.f);
                    wv[j] = (u32)f2b(lo) | ((u32)f2b(hi) << 16);
                }
                va.x = wv[0]; va.y = wv[1]; va.z = wv[2]; va.w = wv[3];
            }
            *reinterpret_cast<uint4*>(&As[(rowi*8 + sw)*8]) = va;
            uint4 vb = *reinterpret_cast<const uint4*>(&Wb[(size_t)(n0+rowi)*256 + k0 + ch*8]);
            *reinterpret_cast<uint4*>(&Bs[(rowi*8 + sw)*8]) = vb;
        }
        __syncthreads();
        const int c = lane >> 4;
        const int rl = lane & 15;
        #pragma unroll
        for (int kt = 0; kt < 2; ++kt) {
            bf16x8 af[4], bfr[4];
            #pragma unroll
            for (int f = 0; f < 4; ++f) {
                int ra = wr*64 + f*16 + rl;
                int cha = (kt*4 + c) ^ (ra & 7);
                af[f] = *reinterpret_cast<const bf16x8*>(&As[(ra*8 + cha)*8]);
                int rb = wc*64 + f*16 + rl;
                int chb = (kt*4 + c) ^ (rb & 7);
                bfr[f] = *reinterpret_cast<const bf16x8*>(&Bs[(rb*8 + chb)*8]);
            }
            #pragma unroll
            for (int fm = 0; fm < 4; ++fm)
                #pragma unroll
                for (int fn = 0; fn < 4; ++fn)
                    acc[fm][fn] = __builtin_amdgcn_mfma_f32_16x16x32_bf16(
                        af[fm], bfr[fn], acc[fm][fn], 0, 0, 0);
        }
        __syncthreads();
    }
    const int cn = lane & 15, rq = lane >> 4;
    #pragma unroll
    for (int fn = 0; fn < 4; ++fn) {
        int n = n0 + wc*64 + fn*16 + cn;
        float bb = bias[n];
        #pragma unroll
        for (int fm = 0; fm < 4; ++fm) {
            #pragma unroll
            for (int r = 0; r < 4; ++r) {
                int m = m0 + wr*64 + fm*16 + rq*4 + r;
                if (m < M) C[(size_t)m*256 + n] = f2b(acc[fm][fn][r] + bb);
            }
        }
    }
}

// ---------------- persistent fused gather + combine + BN-stats ----------------
// Grid-stride over groups of GFB consecutive nodes; per-wave constants loaded once.
// t_new = affine(t_old) + agg + relu(hx+root)*invdeg  (affine = prev layer BN+relu,
// identity for layer 0); writes t in-place; BN stats reduced per block.
#define GFB 4
#define NGROUPS (NN/GFB)
__global__ __launch_bounds__(256) void gather_combine(const int* __restrict__ erow,
        const float* __restrict__ enorm, const u16* __restrict__ eab,
        const int* __restrict__ coff,
        const float* __restrict__ eWt, const float* __restrict__ ebv,
        const u16* __restrict__ hx, const float* __restrict__ rootv,
        const float* __restrict__ invdg, const float* __restrict__ bnscPrev,
        int doBN, u16* __restrict__ t, float* __restrict__ stats, int N)
{
    __shared__ float red[4][512];
    const int wid = threadIdx.x >> 6, lane = threadIdx.x & 63;
    const int f4 = lane*4;
    // per-lane constants (coalesced float4 loads)
    float w[4][10], bb[4];
    #pragma unroll
    for (int k = 0; k < 10; ++k) {
        float4 wv = *reinterpret_cast<const float4*>(&eWt[k*256 + f4]);
        w[0][k] = wv.x; w[1][k] = wv.y; w[2][k] = wv.z; w[3][k] = wv.w;
    }
    { float4 bv = *reinterpret_cast<const float4*>(&ebv[f4]);
      bb[0]=bv.x; bb[1]=bv.y; bb[2]=bv.z; bb[3]=bv.w; }
    float4 root = *reinterpret_cast<const float4*>(&rootv[f4]);
    float sc[4] = {1,1,1,1}, sh[4] = {0,0,0,0};
    if (doBN) {
        float4 s = *reinterpret_cast<const float4*>(&bnscPrev[f4]);
        float4 b = *reinterpret_cast<const float4*>(&bnscPrev[256+f4]);
        sc[0]=s.x; sc[1]=s.y; sc[2]=s.z; sc[3]=s.w;
        sh[0]=b.x; sh[1]=b.y; sh[2]=b.z; sh[3]=b.w;
    }
    float sacc[4] = {0,0,0,0}, s2acc[4] = {0,0,0,0};

    for (int g = blockIdx.x*4 + wid; g < NGROUPS; g += gridDim.x*4) {
        const int nb = g*GFB;
        int c1 = coff[nb+1], c2 = coff[nb+2], c3 = coff[nb+3], c4 = coff[nb+4];
        int s = coff[nb], e = c4;
        int jn = 0, cend = c1;
        float acc[4] = {0,0,0,0};

        #define FLUSH() do {                                                   \
            int n_ = nb + jn;                                                  \
            size_t idx_ = (size_t)n_*EMB + f4;                                 \
            uint2 hv_ = *reinterpret_cast<const uint2*>(&t[idx_]);             \
            uint2 xv_ = *reinterpret_cast<const uint2*>(&hx[idx_]);            \
            float id_ = invdg[n_];                                             \
            float hh_[4] = { b2f((u16)(hv_.x&0xffffu)), b2f((u16)(hv_.x>>16)), \
                             b2f((u16)(hv_.y&0xffffu)), b2f((u16)(hv_.y>>16)) };\
            float xx_[4] = { b2f((u16)(xv_.x&0xffffu)), b2f((u16)(xv_.x>>16)), \
                             b2f((u16)(xv_.y&0xffffu)), b2f((u16)(xv_.y>>16)) };\
            float rt_[4] = { root.x, root.y, root.z, root.w };                 \
            u16 ov_[4];                                                        \
            _Pragma("unroll")                                                  \
            for (int jj = 0; jj < 4; ++jj) {                                   \
                float hin_ = hh_[jj];                                          \
                if (doBN) hin_ = fmaxf(fmaf(hin_, sc[jj], sh[jj]), 0.f);       \
                float rv_ = xx_[jj] + rt_[jj];                                 \
                rv_ = rv_ > 0.f ? rv_ : 0.f;                                   \
                float tv_ = hin_ + acc[jj] + rv_*id_;                          \
                ov_[jj] = f2b(tv_);                                            \
                sacc[jj] += tv_; s2acc[jj] += tv_*tv_;                         \
                acc[jj] = 0.f;                                                 \
            }                                                                  \
            uint2 o_; o_.x = (u32)ov_[0] | ((u32)ov_[1]<<16);                  \
            o_.y = (u32)ov_[2] | ((u32)ov_[3]<<16);                            \
            *reinterpret_cast<uint2*>(&t[idx_]) = o_;                          \
            ++jn; cend = (jn==1) ? c2 : (jn==2) ? c3 : c4;                     \
        } while(0)

        #define CONSUME(nm, hvv, alo, ahi) do {                                \
            float hf_[4] = { b2f((u16)((hvv).x&0xffffu)), b2f((u16)((hvv).x>>16)),\
                             b2f((u16)((hvv).y&0xffffu)), b2f((u16)((hvv).y>>16)) };\
            float at_[10];                                                     \
            at_[0]=b2f((u16)((alo).x&0xffffu)); at_[1]=b2f((u16)((alo).x>>16));\
            at_[2]=b2f((u16)((alo).y&0xffffu)); at_[3]=b2f((u16)((alo).y>>16));\
            at_[4]=b2f((u16)((alo).z&0xffffu)); at_[5]=b2f((u16)((alo).z>>16));\
            at_[6]=b2f((u16)((alo).w&0xffffu)); at_[7]=b2f((u16)((alo).w>>16));\
            at_[8]=b2f((u16)((ahi).x&0xffffu)); at_[9]=b2f((u16)((ahi).x>>16));\
            _Pragma("unroll")                                                  \
            for (int jj = 0; jj < 4; ++jj) {                                   \
                float ea_ = bb[jj];                                            \
                _Pragma("unroll")                                              \
                for (int k = 0; k < 10; ++k) ea_ = fmaf(at_[k], w[jj][k], ea_);\
                float v_ = hf_[jj] + ea_;                                      \
                acc[jj] += v_ > 0.f ? v_*(nm) : 0.f;                           \
            }                                                                  \
        } while(0)

        int p = s;
        for (; p + 4 <= e; p += 4) {
            int r0 = erow[p], r1 = erow[p+1], r2 = erow[p+2], r3 = erow[p+3];
            float n0 = enorm[p], n1 = enorm[p+1], n2 = enorm[p+2], n3 = enorm[p+3];
            uint2 h0 = *reinterpret_cast<const uint2*>(&hx[(size_t)r0*EMB + f4]);
            uint2 h1 = *reinterpret_cast<const uint2*>(&hx[(size_t)r1*EMB + f4]);
            uint2 h2 = *reinterpret_cast<const uint2*>(&hx[(size_t)r2*EMB + f4]);
            uint2 h3 = *reinterpret_cast<const uint2*>(&hx[(size_t)r3*EMB + f4]);
            uint4 a0l = *reinterpret_cast<const uint4*>(&eab[(size_t)(p+0)*16]);
            uint4 a0h = *reinterpret_cast<const uint4*>(&eab[(size_t)(p+0)*16+8]);
            uint4 a1l = *reinterpret_cast<const uint4*>(&eab[(size_t)(p+1)*16]);
            uint4 a1h = *reinterpret_cast<const uint4*>(&eab[(size_t)(p+1)*16+8]);
            uint4 a2l = *reinterpret_cast<const uint4*>(&eab[(size_t)(p+2)*16]);
            uint4 a2h = *reinterpret_cast<const uint4*>(&eab[(size_t)(p+2)*16+8]);
            uint4 a3l = *reinterpret_cast<const uint4*>(&eab[(size_t)(p+3)*16]);
            uint4 a3h = *reinterpret_cast<const uint4*>(&eab[(size_t)(p+3)*16+8]);
            while (p+0 >= cend) FLUSH();
            CONSUME(n0, h0, a0l, a0h);
            while (p+1 >= cend) FLUSH();
            CONSUME(n1, h1, a1l, a1h);
            while (p+2 >= cend) FLUSH();
            CONSUME(n2, h2, a2l, a2h);
            while (p+3 >= cend) FLUSH();
            CONSUME(n3, h3, a3l, a3h);
        }
        for (; p < e; ++p) {
            int r0 = erow[p];
            float n0 = enorm[p];
            uint2 h0 = *reinterpret_cast<const uint2*>(&hx[(size_t)r0*EMB + f4]);
            uint4 a0l = *reinterpret_cast<const uint4*>(&eab[(size_t)p*16]);
            uint4 a0h = *reinterpret_cast<const uint4*>(&eab[(size_t)p*16+8]);
            while (p >= cend) FLUSH();
            CONSUME(n0, h0, a0l, a0h);
        }
        while (jn < GFB) FLUSH();
        #undef FLUSH
        #undef CONSUME
    }

    #pragma unroll
    for (int j = 0; j < 4; ++j) {
        red[wid][f4+j]     = sacc[j];
        red[wid][256+f4+j] = s2acc[j];
    }
    __syncthreads();
    int tt = threadIdx.x;
    float a0 = red[0][tt] + red[1][tt] + red[2][tt] + red[3][tt];
    float a1 = red[0][256+tt] + red[1][256+tt] + red[2][256+tt] + red[3][256+tt];
    atomicAdd(&stats[tt], a0);
    atomicAdd(&stats[256+tt], a1);
}

// ---------------- BN finalize ----------------
__global__ void bn_finalize(const float* __restrict__ stats,
        const float* __restrict__ gamma, const float* __restrict__ beta,
        float* __restrict__ sc, int N)
{
    int f = threadIdx.x;
    float inv = 1.0f / (float)N;
    float mean = stats[f] * inv;
    float var  = stats[256+f] * inv - mean*mean;
    float is = rsqrtf(var + 1e-5f);
    float scale = gamma[f] * is;
    sc[f] = scale;
    sc[256+f] = fmaf(-mean, scale, beta[f]);
}

// ---------------- mean pool over sorted batch (applies final BN, no relu) -----
__global__ __launch_bounds__(256) void pool_kernel(const u16* __restrict__ t,
        const int* __restrict__ batch, const float* __restrict__ bnsc4,
        float* __restrict__ psum, float* __restrict__ pcnt, int N)
{
    int f = threadIdx.x;
    float sc = bnsc4[f], shb = bnsc4[256+f];
    int n0 = blockIdx.x * 256;
    int n1 = min(n0 + 256, N);
    int cur = batch[n0];
    float acc = 0.f;
    int cnt = 0;
    for (int n = n0; n < n1; ++n) {
        int g = batch[n];
        if (g != cur) {
            atomicAdd(&psum[(size_t)cur*EMB + f], acc);
            if (f == 0) atomicAdd(&pcnt[cur], (float)cnt);
            acc = 0.f; cnt = 0; cur = g;
        }
        acc += fmaf(b2f(t[(size_t)n*EMB + f]), sc, shb);
        ++cnt;
    }
    atomicAdd(&psum[(size_t)cur*EMB + f], acc);
    if (f == 0) atomicAdd(&pcnt[cur], (float)cnt);
}

// ---------------- fused MLP head ----------------
__global__ __launch_bounds__(128) void head_kernel(const float* __restrict__ psum,
        const float* __restrict__ pcnt,
        const float* __restrict__ p1W, const float* __restrict__ p1b,
        const float* __restrict__ p2W, const float* __restrict__ p2b,
        const float* __restrict__ p3W, const float* __restrict__ p3b,
        float* __restrict__ out)
{
    __shared__ float gs[256];
    __shared__ float h1[128];
    __shared__ float h2[128];
    __shared__ float red[2];
    int g = blockIdx.x, t = threadIdx.x;
    float invc = 1.0f / fmaxf(pcnt[g], 1.0f);
    gs[t]       = psum[(size_t)g*EMB + t] * invc;
    gs[t + 128] = psum[(size_t)g*EMB + 128 + t] * invc;
    __syncthreads();
    float a = p1b[t];
    for (int k = 0; k < 256; ++k) a = fmaf(p1W[(size_t)t*256 + k], gs[k], a);
    h1[t] = fmaxf(a, 0.f);
    __syncthreads();
    float b = p2b[t];
    for (int k = 0; k < 128; ++k) b = fmaf(p2W[(size_t)t*128 + k], h1[k], b);
    h2[t] = fmaxf(b, 0.f);
    __syncthreads();
    float r = p3W[t] * h2[t];
    for (int off = 32; off > 0; off >>= 1) r += __shfl_down(r, off);
    if ((t & 63) == 0) red[t >> 6] = r;
    __syncthreads();
    if (t == 0) out[g] = red[0] + red[1] + p3b[0];
}

extern "C" void kernel_launch(void* const* d_in, const int* in_sizes, int n_in,
                              void* d_out, int out_size, void* d_ws, size_t ws_size,
                              hipStream_t stream)
{
    const float* x     = (const float*)d_in[0];
    const int*   eidx  = (const int*)d_in[1];
    const float* eattr = (const float*)d_in[2];
    const int*   batch = (const int*)d_in[3];
    const float* xW    = (const float*)d_in[4];
    const float* xb    = (const float*)d_in[5];
    const float* eW    = (const float*)d_in[6];
    const float* eb    = (const float*)d_in[7];
    const float* gcnW  = (const float*)d_in[8];
    const float* gcnb  = (const float*)d_in[9];
    const float* rootE = (const float*)d_in[10];
    const float* bng   = (const float*)d_in[11];
    const float* bnb   = (const float*)d_in[12];
    const float* p1W   = (const float*)d_in[13];
    const float* p1b   = (const float*)d_in[14];
    const float* p2W   = (const float*)d_in[15];
    const float* p2b   = (const float*)d_in[16];
    const float* p3W   = (const float*)d_in[17];
    const float* p3b   = (const float*)d_in[18];
    float* out = (float*)d_out;

    const int* row = eidx;
    const int* col = eidx + NE;

    const size_t HSZ = (size_t)NN * EMB;            // 25.6M elements
    const int NWB = 5*EMB*EMB;                      // 327680

    // ---- ws layout ----
    char* p = (char*)d_ws;
    u16* t   = (u16*)p;            p += HSZ*2;      // pre-BN state
    u16* hx  = (u16*)p;            p += HSZ*2;      // GEMM output
    u16* Wb  = (u16*)p;            p += (size_t)NWB*2;
    float* eWt = (float*)p;        p += 2560*4;
    // zeroed accumulator region
    char* zbase = p;
    int* rcnt   = (int*)p;         p += (size_t)NN*4;
    int* ccnt   = (int*)p;         p += (size_t)NN*4;
    int* fill   = (int*)p;         p += (size_t)NN*4;
    float* stats= (float*)p;       p += (size_t)NLAYERS*512*4;
    float* psum = (float*)p;       p += (size_t)NG*EMB*4;
    float* pcnt = (float*)p;       p += (size_t)NG*4;
    size_t zbytes = (size_t)(p - zbase);
    float* dinv = (float*)p;       p += (size_t)NN*4;
    float* invdg= (float*)p;       p += (size_t)NN*4;
    float* bnscA= (float*)p;       p += (size_t)NLAYERS*512*4;
    int* coff   = (int*)p;         p += (size_t)(NN+1)*4;
    int* bsum   = (int*)p;         p += 512*4;
    int* bbase  = (int*)p;         p += 512*4;
    int* erow   = (int*)p;         p += (size_t)NE*4;
    float* enorm= (float*)p;       p += (size_t)NE*4;
    u16* eab    = (u16*)p;         p += (size_t)NE*16*2;
    size_t NEED = (size_t)(p - (char*)d_ws);
    if (ws_size < NEED) return;    // fail absmax cleanly instead of faulting

    hipMemsetAsync(zbase, 0, zbytes, stream);

    const int NBS = (NN + 255)/256;

    embed_x<<<NN/XNB, 256, 0, stream>>>(x, xW, xb, t);
    wconv<<<(NWB+255)/256, 256, 0, stream>>>(gcnW, Wb, NWB);
    ewt_kernel<<<10, 256, 0, stream>>>(eW, eWt);
    hist_kernel<<<(NE+255)/256, 256, 0, stream>>>(row, col, rcnt, ccnt, NE);
    deg_fin<<<NBS, 256, 0, stream>>>(rcnt, dinv, invdg, NN);
    scan1<<<NBS, 256, 0, stream>>>(ccnt, bsum, NN);
    scan2<<<1, 512, 0, stream>>>(bsum, bbase, coff, NBS);
    scan3<<<NBS, 256, 0, stream>>>(ccnt, bbase, coff, NN);
    csr_fill<<<(NE+255)/256, 256, 0, stream>>>(row, col, eattr, coff, dinv, fill,
                                               erow, enorm, eab, NE);

    for (int l = 0; l < NLAYERS; ++l) {
        const u16*   Wl = Wb + (size_t)l*EMB*EMB;
        const float* bl = gcnb + (size_t)l*EMB;
        const float* rl = rootE + (size_t)l*EMB;
        const float* scPrev = bnscA + (size_t)(l > 0 ? l-1 : 0)*512;
        int doBN = (l > 0) ? 1 : 0;
        dim3 ggrid((NN + BM - 1)/BM, EMB/BM);
        gemm_mfma<<<ggrid, 256, 0, stream>>>(t, Wl, bl, scPrev, doBN, hx, NN);
        gather_combine<<<1536, 256, 0, stream>>>(erow, enorm, eab, coff, eWt, eb,
                hx, rl, invdg, scPrev, doBN, t, stats + l*512, NN);
        bn_finalize<<<1, 256, 0, stream>>>(stats + l*512, bng + (size_t)l*EMB,
                                           bnb + (size_t)l*EMB, bnscA + (size_t)l*512, NN);
    }

    pool_kernel<<<NBS, 256, 0, stream>>>(t, batch, bnscA + (size_t)(NLAYERS-1)*512,
                                         psum, pcnt, NN);
    head_kernel<<<NG, 128, 0, stream>>>(psum, pcnt, p1W, p1b, p2W, p2b, p3W, p3b, out);
}

// Round 7
// 970.128 us; speedup vs baseline: 1.4807x; 1.0378x over previous
//
#include <hip/hip_runtime.h>
#include <hip/hip_bf16.h>

#define NN 100000
#define NE 300000
#define NG 4096
#define EMB 256
#define NLAYERS 5

typedef unsigned short u16;
typedef unsigned int u32;

typedef short bf16x8 __attribute__((ext_vector_type(8)));
typedef float f32x4 __attribute__((ext_vector_type(4)));

__device__ __forceinline__ float b2f(u16 u){
    union { float f; u32 i; } v; v.i = ((u32)u) << 16; return v.f;
}
__device__ __forceinline__ u16 f2b(float f){
    __hip_bfloat16 h = __float2bfloat16(f);   // RNE
    union { __hip_bfloat16 h; u16 u; } v; v.h = h; return v.u;
}

// ---------------- x embedding: t = x @ xW.T + xb  (bf16 out, raw/pre-BN) ------
#define XNB 32
__global__ __launch_bounds__(256) void embed_x(const float* __restrict__ x,
        const float* __restrict__ W, const float* __restrict__ b,
        u16* __restrict__ t)
{
    __shared__ float sW[256][41];
    __shared__ float sx[XNB][40];
    int tid = threadIdx.x;
    for (int i = tid; i < 256*40; i += 256) sW[i/40][i%40] = W[i];
    int n0 = blockIdx.x * XNB;      // 100000 = 3125*32 exact
    for (int i = tid; i < XNB*40; i += 256) {
        int j = i/40, k = i%40;
        sx[j][k] = x[(size_t)(n0+j)*40 + k];
    }
    __syncthreads();
    float bb = b[tid];
    for (int j = 0; j < XNB; ++j) {
        float a = bb;
        #pragma unroll
        for (int k = 0; k < 40; ++k) a = fmaf(sW[tid][k], sx[j][k], a);
        t[(size_t)(n0+j)*EMB + tid] = f2b(a);
    }
}

// ---------------- W -> bf16 ----------------
__global__ void wconv(const float* __restrict__ W, u16* __restrict__ Wb, int n)
{
    int i = blockIdx.x*256 + threadIdx.x;
    if (i < n) Wb[i] = f2b(W[i]);
}

// ---------------- eW transpose: eWt[k*256+f] = eW[f*10+k] ----------------
__global__ void ewt_kernel(const float* __restrict__ eW, float* __restrict__ eWt)
{
    int i = blockIdx.x*256 + threadIdx.x;
    if (i < 2560) { int f = i/10, k = i%10; eWt[k*256 + f] = eW[i]; }
}

// ---------------- histograms ----------------
__global__ void hist_kernel(const int* __restrict__ row, const int* __restrict__ col,
        int* __restrict__ rcnt, int* __restrict__ ccnt, int E)
{
    int e = blockIdx.x*256 + threadIdx.x;
    if (e < E) {
        atomicAdd(&rcnt[row[e]], 1);
        atomicAdd(&ccnt[col[e]], 1);
    }
}

__global__ void deg_fin(const int* __restrict__ rcnt, float* __restrict__ dinv,
                        float* __restrict__ invdg, int N)
{
    int n = blockIdx.x*256 + threadIdx.x;
    if (n < N) {
        float d = (float)rcnt[n] + 1.0f;
        dinv[n]  = rsqrtf(d);
        invdg[n] = 1.0f/d;
    }
}

// ---------------- prefix scan (3 kernels) ----------------
__global__ void scan1(const int* __restrict__ cnt, int* __restrict__ bsum, int N)
{
    __shared__ int sh[256];
    int t = threadIdx.x, i = blockIdx.x*256 + t;
    sh[t] = (i < N) ? cnt[i] : 0;
    __syncthreads();
    for (int off = 128; off > 0; off >>= 1) {
        if (t < off) sh[t] += sh[t+off];
        __syncthreads();
    }
    if (t == 0) bsum[blockIdx.x] = sh[0];
}

__global__ __launch_bounds__(512) void scan2(const int* __restrict__ bsum,
        int* __restrict__ bbase, int* __restrict__ coff, int nb)
{
    __shared__ int a[512], b[512];
    int t = threadIdx.x;
    a[t] = (t < nb) ? bsum[t] : 0;
    __syncthreads();
    int* src = a; int* dst = b;
    for (int off = 1; off < 512; off <<= 1) {
        dst[t] = (t >= off) ? src[t-off] + src[t] : src[t];
        __syncthreads();
        int* tmp = src; src = dst; dst = tmp;
    }
    bbase[t] = t ? src[t-1] : 0;
    if (t == 0) coff[NN] = NE;
}

__global__ void scan3(const int* __restrict__ cnt, const int* __restrict__ bbase,
        int* __restrict__ coff, int N)
{
    __shared__ int a[256], b[256];
    int t = threadIdx.x, i = blockIdx.x*256 + t;
    a[t] = (i < N) ? cnt[i] : 0;
    __syncthreads();
    int* src = a; int* dst = b;
    for (int off = 1; off < 256; off <<= 1) {
        dst[t] = (t >= off) ? src[t-off] + src[t] : src[t];
        __syncthreads();
        int* tmp = src; src = dst; dst = tmp;
    }
    if (i < N) coff[i] = bbase[blockIdx.x] + (t ? src[t-1] : 0);
}

// CSR fill: per-edge streams in CSR(col) order.
__global__ void csr_fill(const int* __restrict__ row, const int* __restrict__ col,
        const float* __restrict__ eattr, const int* __restrict__ coff,
        const float* __restrict__ dinv, int* __restrict__ fill,
        int* __restrict__ erow, float* __restrict__ enorm,
        u16* __restrict__ eab, int E)
{
    int e = blockIdx.x*256 + threadIdx.x;
    if (e < E) {
        int c = col[e], r = row[e];
        int p = coff[c] + atomicAdd(&fill[c], 1);
        erow[p]  = r;
        enorm[p] = dinv[r] * dinv[c];
        #pragma unroll
        for (int k = 0; k < 10; ++k) eab[(size_t)p*16 + k] = f2b(eattr[(size_t)e*10 + k]);
        #pragma unroll
        for (int k = 10; k < 16; ++k) eab[(size_t)p*16 + k] = 0;
    }
}

// ---------------- MFMA GEMM, full-width (BN=256), 8 waves, fused input-BN -----
// C[m][o] = sum_k affine(A[m][k]) * Wb[o][k] + bias[o]
// affine (doBN=1): a -> relu(a*sc[k]+sh[k]); else identity. A fetched ONCE.
__global__ __launch_bounds__(512) void gemm_mfma(const u16* __restrict__ A,
        const u16* __restrict__ Wb, const float* __restrict__ bias,
        const float* __restrict__ bnsc, int doBN,
        u16* __restrict__ C, int M)
{
    __shared__ u16 As[128*64];   // 16B chunk idx = row*8 + (ch ^ (row&7))
    __shared__ u16 Bs[256*64];
    __shared__ float scS[256], shS[256];
    const int tid = threadIdx.x;
    if (doBN && tid < 256) { scS[tid] = bnsc[tid]; shS[tid] = bnsc[256+tid]; }
    const int wid  = tid >> 6;
    const int lane = tid & 63;
    const int wm = wid >> 2, wn = wid & 3;   // 2(M) x 4(N) waves, 64x64 each
    const int m0 = blockIdx.x * 128;
    __syncthreads();
    f32x4 acc[4][4] = {};
    for (int k0 = 0; k0 < 256; k0 += 64) {
        // A: 1024 chunks (128 rows x 8), affine applied
        #pragma unroll
        for (int i = 0; i < 2; ++i) {
            int L = tid + i*512;
            int rowi = L >> 3, ch = L & 7;
            int sw = ch ^ (rowi & 7);
            int gr = m0 + rowi; gr = gr < M ? gr : M-1;
            uint4 va = *reinterpret_cast<const uint4*>(&A[(size_t)gr*256 + k0 + ch*8]);
            if (doBN) {
                int kk = k0 + ch*8;
                u32 wv[4] = {va.x, va.y, va.z, va.w};
                #pragma unroll
                for (int j = 0; j < 4; ++j) {
                    float lo = b2f((u16)(wv[j] & 0xffffu));
                    float hi = b2f((u16)(wv[j] >> 16));
                    lo = fmaxf(fmaf(lo, scS[kk+2*j],   shS[kk+2*j]),   0.f);
                    hi = fmaxf(fmaf(hi, scS[kk+2*j+1], shS[kk+2*j+1]), 0.f);
                    wv[j] = (u32)f2b(lo) | ((u32)f2b(hi) << 16);
                }
                va.x = wv[0]; va.y = wv[1]; va.z = wv[2]; va.w = wv[3];
            }
            *reinterpret_cast<uint4*>(&As[(rowi*8 + sw)*8]) = va;
        }
        // B: 2048 chunks (256 rows x 8)
        #pragma unroll
        for (int i = 0; i < 4; ++i) {
            int L = tid + i*512;
            int rowi = L >> 3, ch = L & 7;
            int sw = ch ^ (rowi & 7);
            uint4 vb = *reinterpret_cast<const uint4*>(&Wb[(size_t)rowi*256 + k0 + ch*8]);
            *reinterpret_cast<uint4*>(&Bs[(rowi*8 + sw)*8]) = vb;
        }
        __syncthreads();
        const int c = lane >> 4;
        const int rl = lane & 15;
        #pragma unroll
        for (int kt = 0; kt < 2; ++kt) {
            bf16x8 af[4], bfr[4];
            #pragma unroll
            for (int f = 0; f < 4; ++f) {
                int ra = wm*64 + f*16 + rl;
                int cha = (kt*4 + c) ^ (ra & 7);
                af[f] = *reinterpret_cast<const bf16x8*>(&As[(ra*8 + cha)*8]);
                int rb = wn*64 + f*16 + rl;
                int chb = (kt*4 + c) ^ (rb & 7);
                bfr[f] = *reinterpret_cast<const bf16x8*>(&Bs[(rb*8 + chb)*8]);
            }
            #pragma unroll
            for (int fm = 0; fm < 4; ++fm)
                #pragma unroll
                for (int fn = 0; fn < 4; ++fn)
                    acc[fm][fn] = __builtin_amdgcn_mfma_f32_16x16x32_bf16(
                        af[fm], bfr[fn], acc[fm][fn], 0, 0, 0);
        }
        __syncthreads();
    }
    const int cn = lane & 15, rq = lane >> 4;
    #pragma unroll
    for (int fn = 0; fn < 4; ++fn) {
        int n = wn*64 + fn*16 + cn;
        float bb = bias[n];
        #pragma unroll
        for (int fm = 0; fm < 4; ++fm) {
            #pragma unroll
            for (int r = 0; r < 4; ++r) {
                int m = m0 + wm*64 + fm*16 + rq*4 + r;
                if (m < M) C[(size_t)m*256 + n] = f2b(acc[fm][fn][r] + bb);
            }
        }
    }
}

// ---------------- persistent fused gather + combine + BN-stats ----------------
#define GFB 4
#define NGROUPS (NN/GFB)
__global__ __launch_bounds__(256) void gather_combine(const int* __restrict__ erow,
        const float* __restrict__ enorm, const u16* __restrict__ eab,
        const int* __restrict__ coff,
        const float* __restrict__ eWt, const float* __restrict__ ebv,
        const u16* __restrict__ hx, const float* __restrict__ rootv,
        const float* __restrict__ invdg, const float* __restrict__ bnscPrev,
        int doBN, u16* __restrict__ t, float* __restrict__ stats, int N)
{
    __shared__ float red[4][512];
    const int wid = threadIdx.x >> 6, lane = threadIdx.x & 63;
    const int f4 = lane*4;
    float w[4][10], bb[4];
    #pragma unroll
    for (int k = 0; k < 10; ++k) {
        float4 wv = *reinterpret_cast<const float4*>(&eWt[k*256 + f4]);
        w[0][k] = wv.x; w[1][k] = wv.y; w[2][k] = wv.z; w[3][k] = wv.w;
    }
    { float4 bv = *reinterpret_cast<const float4*>(&ebv[f4]);
      bb[0]=bv.x; bb[1]=bv.y; bb[2]=bv.z; bb[3]=bv.w; }
    float4 root = *reinterpret_cast<const float4*>(&rootv[f4]);
    float sc[4] = {1,1,1,1}, sh[4] = {0,0,0,0};
    if (doBN) {
        float4 s = *reinterpret_cast<const float4*>(&bnscPrev[f4]);
        float4 b = *reinterpret_cast<const float4*>(&bnscPrev[256+f4]);
        sc[0]=s.x; sc[1]=s.y; sc[2]=s.z; sc[3]=s.w;
        sh[0]=b.x; sh[1]=b.y; sh[2]=b.z; sh[3]=b.w;
    }
    float sacc[4] = {0,0,0,0}, s2acc[4] = {0,0,0,0};

    for (int g = blockIdx.x*4 + wid; g < NGROUPS; g += gridDim.x*4) {
        const int nb = g*GFB;
        int c1 = coff[nb+1], c2 = coff[nb+2], c3 = coff[nb+3], c4 = coff[nb+4];
        int s = coff[nb], e = c4;
        int jn = 0, cend = c1;
        float acc[4] = {0,0,0,0};

        #define FLUSH() do {                                                   \
            int n_ = nb + jn;                                                  \
            size_t idx_ = (size_t)n_*EMB + f4;                                 \
            uint2 hv_ = *reinterpret_cast<const uint2*>(&t[idx_]);             \
            uint2 xv_ = *reinterpret_cast<const uint2*>(&hx[idx_]);            \
            float id_ = invdg[n_];                                             \
            float hh_[4] = { b2f((u16)(hv_.x&0xffffu)), b2f((u16)(hv_.x>>16)), \
                             b2f((u16)(hv_.y&0xffffu)), b2f((u16)(hv_.y>>16)) };\
            float xx_[4] = { b2f((u16)(xv_.x&0xffffu)), b2f((u16)(xv_.x>>16)), \
                             b2f((u16)(xv_.y&0xffffu)), b2f((u16)(xv_.y>>16)) };\
            float rt_[4] = { root.x, root.y, root.z, root.w };                 \
            u16 ov_[4];                                                        \
            _Pragma("unroll")                                                  \
            for (int jj = 0; jj < 4; ++jj) {                                   \
                float hin_ = hh_[jj];                                          \
                if (doBN) hin_ = fmaxf(fmaf(hin_, sc[jj], sh[jj]), 0.f);       \
                float rv_ = xx_[jj] + rt_[jj];                                 \
                rv_ = rv_ > 0.f ? rv_ : 0.f;                                   \
                float tv_ = hin_ + acc[jj] + rv_*id_;                          \
                ov_[jj] = f2b(tv_);                                            \
                sacc[jj] += tv_; s2acc[jj] += tv_*tv_;                         \
                acc[jj] = 0.f;                                                 \
            }                                                                  \
            uint2 o_; o_.x = (u32)ov_[0] | ((u32)ov_[1]<<16);                  \
            o_.y = (u32)ov_[2] | ((u32)ov_[3]<<16);                            \
            *reinterpret_cast<uint2*>(&t[idx_]) = o_;                          \
            ++jn; cend = (jn==1) ? c2 : (jn==2) ? c3 : c4;                     \
        } while(0)

        #define CONSUME(nm, hvv, alo, ahi) do {                                \
            float hf_[4] = { b2f((u16)((hvv).x&0xffffu)), b2f((u16)((hvv).x>>16)),\
                             b2f((u16)((hvv).y&0xffffu)), b2f((u16)((hvv).y>>16)) };\
            float at_[10];                                                     \
            at_[0]=b2f((u16)((alo).x&0xffffu)); at_[1]=b2f((u16)((alo).x>>16));\
            at_[2]=b2f((u16)((alo).y&0xffffu)); at_[3]=b2f((u16)((alo).y>>16));\
            at_[4]=b2f((u16)((alo).z&0xffffu)); at_[5]=b2f((u16)((alo).z>>16));\
            at_[6]=b2f((u16)((alo).w&0xffffu)); at_[7]=b2f((u16)((alo).w>>16));\
            at_[8]=b2f((u16)((ahi).x&0xffffu)); at_[9]=b2f((u16)((ahi).x>>16));\
            _Pragma("unroll")                                                  \
            for (int jj = 0; jj < 4; ++jj) {                                   \
                float ea_ = bb[jj];                                            \
                _Pragma("unroll")                                              \
                for (int k = 0; k < 10; ++k) ea_ = fmaf(at_[k], w[jj][k], ea_);\
                float v_ = hf_[jj] + ea_;                                      \
                acc[jj] += v_ > 0.f ? v_*(nm) : 0.f;                           \
            }                                                                  \
        } while(0)

        int p = s;
        for (; p + 4 <= e; p += 4) {
            int r0 = erow[p], r1 = erow[p+1], r2 = erow[p+2], r3 = erow[p+3];
            float n0 = enorm[p], n1 = enorm[p+1], n2 = enorm[p+2], n3 = enorm[p+3];
            uint2 h0 = *reinterpret_cast<const uint2*>(&hx[(size_t)r0*EMB + f4]);
            uint2 h1 = *reinterpret_cast<const uint2*>(&hx[(size_t)r1*EMB + f4]);
            uint2 h2 = *reinterpret_cast<const uint2*>(&hx[(size_t)r2*EMB + f4]);
            uint2 h3 = *reinterpret_cast<const uint2*>(&hx[(size_t)r3*EMB + f4]);
            uint4 a0l = *reinterpret_cast<const uint4*>(&eab[(size_t)(p+0)*16]);
            uint4 a0h = *reinterpret_cast<const uint4*>(&eab[(size_t)(p+0)*16+8]);
            uint4 a1l = *reinterpret_cast<const uint4*>(&eab[(size_t)(p+1)*16]);
            uint4 a1h = *reinterpret_cast<const uint4*>(&eab[(size_t)(p+1)*16+8]);
            uint4 a2l = *reinterpret_cast<const uint4*>(&eab[(size_t)(p+2)*16]);
            uint4 a2h = *reinterpret_cast<const uint4*>(&eab[(size_t)(p+2)*16+8]);
            uint4 a3l = *reinterpret_cast<const uint4*>(&eab[(size_t)(p+3)*16]);
            uint4 a3h = *reinterpret_cast<const uint4*>(&eab[(size_t)(p+3)*16+8]);
            while (p+0 >= cend) FLUSH();
            CONSUME(n0, h0, a0l, a0h);
            while (p+1 >= cend) FLUSH();
            CONSUME(n1, h1, a1l, a1h);
            while (p+2 >= cend) FLUSH();
            CONSUME(n2, h2, a2l, a2h);
            while (p+3 >= cend) FLUSH();
            CONSUME(n3, h3, a3l, a3h);
        }
        for (; p < e; ++p) {
            int r0 = erow[p];
            float n0 = enorm[p];
            uint2 h0 = *reinterpret_cast<const uint2*>(&hx[(size_t)r0*EMB + f4]);
            uint4 a0l = *reinterpret_cast<const uint4*>(&eab[(size_t)p*16]);
            uint4 a0h = *reinterpret_cast<const uint4*>(&eab[(size_t)p*16+8]);
            while (p >= cend) FLUSH();
            CONSUME(n0, h0, a0l, a0h);
        }
        while (jn < GFB) FLUSH();
        #undef FLUSH
        #undef CONSUME
    }

    #pragma unroll
    for (int j = 0; j < 4; ++j) {
        red[wid][f4+j]     = sacc[j];
        red[wid][256+f4+j] = s2acc[j];
    }
    __syncthreads();
    int tt = threadIdx.x;
    float a0 = red[0][tt] + red[1][tt] + red[2][tt] + red[3][tt];
    float a1 = red[0][256+tt] + red[1][256+tt] + red[2][256+tt] + red[3][256+tt];
    atomicAdd(&stats[tt], a0);
    atomicAdd(&stats[256+tt], a1);
}

// ---------------- BN finalize ----------------
__global__ void bn_finalize(const float* __restrict__ stats,
        const float* __restrict__ gamma, const float* __restrict__ beta,
        float* __restrict__ sc, int N)
{
    int f = threadIdx.x;
    float inv = 1.0f / (float)N;
    float mean = stats[f] * inv;
    float var  = stats[256+f] * inv - mean*mean;
    float is = rsqrtf(var + 1e-5f);
    float scale = gamma[f] * is;
    sc[f] = scale;
    sc[256+f] = fmaf(-mean, scale, beta[f]);
}

// ---------------- mean pool (applies final BN), uint loads, 2-node interleave -
__global__ __launch_bounds__(256) void pool_kernel(const u16* __restrict__ t,
        const int* __restrict__ batch, const float* __restrict__ bnsc4,
        float* __restrict__ psum, float* __restrict__ pcnt, int N)
{
    int tid = threadIdx.x;
    int half = tid >> 7;          // 0/1: even/odd nodes
    int pp = tid & 127;           // feature pair
    const u32* t32 = (const u32*)t;
    float sc0 = bnsc4[2*pp],     sc1 = bnsc4[2*pp+1];
    float sh0 = bnsc4[256+2*pp], sh1 = bnsc4[256+2*pp+1];
    int n0 = blockIdx.x * 256;
    int n1 = min(n0 + 256, N);
    int start = n0 + half;
    if (start >= n1) return;
    int cur = batch[start];
    float a0 = 0.f, a1 = 0.f;
    int cnt = 0;
    for (int n = start; n < n1; n += 2) {
        int gb = batch[n];
        if (gb != cur) {
            atomicAdd(&psum[(size_t)cur*EMB + 2*pp],   a0);
            atomicAdd(&psum[(size_t)cur*EMB + 2*pp+1], a1);
            if (pp == 0) atomicAdd(&pcnt[cur], (float)cnt);
            a0 = a1 = 0.f; cnt = 0; cur = gb;
        }
        u32 v = t32[(size_t)n*128 + pp];
        a0 += fmaf(b2f((u16)(v & 0xffffu)), sc0, sh0);
        a1 += fmaf(b2f((u16)(v >> 16)),     sc1, sh1);
        ++cnt;
    }
    atomicAdd(&psum[(size_t)cur*EMB + 2*pp],   a0);
    atomicAdd(&psum[(size_t)cur*EMB + 2*pp+1], a1);
    if (pp == 0) atomicAdd(&pcnt[cur], (float)cnt);
}

// ---------------- g = psum/cnt  (bf16 out) ----------------
__global__ void pool2g(const float* __restrict__ psum, const float* __restrict__ pcnt,
        u16* __restrict__ gbf)
{
    int i = blockIdx.x*256 + threadIdx.x;    // over NG*128 pairs
    if (i < NG*128) {
        int g = i >> 7, p2 = (i & 127)*2;
        float invc = 1.0f / fmaxf(pcnt[g], 1.0f);
        u32 pk = (u32)f2b(psum[(size_t)g*EMB + p2] * invc)
               | ((u32)f2b(psum[(size_t)g*EMB + p2 + 1] * invc) << 16);
        ((u32*)gbf)[i] = pk;
    }
}

// ---------------- head GEMM: C = relu(A @ W.T + b), N=128, K param ------------
__global__ __launch_bounds__(256) void gemm_head(const u16* __restrict__ A,
        const u16* __restrict__ W, const float* __restrict__ bias,
        u16* __restrict__ C, int M, int K)
{
    __shared__ u16 As[128*64];
    __shared__ u16 Bs[128*64];
    const int tid  = threadIdx.x;
    const int wid  = tid >> 6;
    const int lane = tid & 63;
    const int wr = wid >> 1, wc = wid & 1;
    const int m0 = blockIdx.x * 128;
    f32x4 acc[4][4] = {};
    for (int k0 = 0; k0 < K; k0 += 64) {
        #pragma unroll
        for (int i = 0; i < 4; ++i) {
            int L = tid + i*256;
            int rowi = L >> 3, ch = L & 7;
            int sw = ch ^ (rowi & 7);
            int gr = m0 + rowi; gr = gr < M ? gr : M-1;
            uint4 va = *reinterpret_cast<const uint4*>(&A[(size_t)gr*K + k0 + ch*8]);
            *reinterpret_cast<uint4*>(&As[(rowi*8 + sw)*8]) = va;
            uint4 vb = *reinterpret_cast<const uint4*>(&W[(size_t)rowi*K + k0 + ch*8]);
            *reinterpret_cast<uint4*>(&Bs[(rowi*8 + sw)*8]) = vb;
        }
        __syncthreads();
        const int c = lane >> 4;
        const int rl = lane & 15;
        #pragma unroll
        for (int kt = 0; kt < 2; ++kt) {
            bf16x8 af[4], bfr[4];
            #pragma unroll
            for (int f = 0; f < 4; ++f) {
                int ra = wr*64 + f*16 + rl;
                int cha = (kt*4 + c) ^ (ra & 7);
                af[f] = *reinterpret_cast<const bf16x8*>(&As[(ra*8 + cha)*8]);
                int rb = wc*64 + f*16 + rl;
                int chb = (kt*4 + c) ^ (rb & 7);
                bfr[f] = *reinterpret_cast<const bf16x8*>(&Bs[(rb*8 + chb)*8]);
            }
            #pragma unroll
            for (int fm = 0; fm < 4; ++fm)
                #pragma unroll
                for (int fn = 0; fn < 4; ++fn)
                    acc[fm][fn] = __builtin_amdgcn_mfma_f32_16x16x32_bf16(
                        af[fm], bfr[fn], acc[fm][fn], 0, 0, 0);
        }
        __syncthreads();
    }
    const int cn = lane & 15, rq = lane >> 4;
    #pragma unroll
    for (int fn = 0; fn < 4; ++fn) {
        int n = wc*64 + fn*16 + cn;
        float bb = bias[n];
        #pragma unroll
        for (int fm = 0; fm < 4; ++fm) {
            #pragma unroll
            for (int r = 0; r < 4; ++r) {
                int m = m0 + wr*64 + fm*16 + rq*4 + r;
                if (m < M) C[(size_t)m*128 + n] = f2b(fmaxf(acc[fm][fn][r] + bb, 0.f));
            }
        }
    }
}

// ---------------- head final: out[g] = dot(h2[g], p3W) + p3b ----------------
__global__ __launch_bounds__(256) void head_final(const u16* __restrict__ h2,
        const float* __restrict__ p3W, const float* __restrict__ p3b,
        float* __restrict__ out, int G)
{
    int tid = blockIdx.x*256 + threadIdx.x;
    int g = tid >> 4, sub = tid & 15;
    if (g >= G) return;
    uint4 v = *reinterpret_cast<const uint4*>(&h2[(size_t)g*128 + sub*8]);
    u32 wv[4] = {v.x, v.y, v.z, v.w};
    float s = 0.f;
    #pragma unroll
    for (int j = 0; j < 4; ++j) {
        s = fmaf(b2f((u16)(wv[j] & 0xffffu)), p3W[sub*8 + 2*j],   s);
        s = fmaf(b2f((u16)(wv[j] >> 16)),     p3W[sub*8 + 2*j+1], s);
    }
    s += __shfl_down(s, 8, 16);
    s += __shfl_down(s, 4, 16);
    s += __shfl_down(s, 2, 16);
    s += __shfl_down(s, 1, 16);
    if (sub == 0) out[g] = s + p3b[0];
}

extern "C" void kernel_launch(void* const* d_in, const int* in_sizes, int n_in,
                              void* d_out, int out_size, void* d_ws, size_t ws_size,
                              hipStream_t stream)
{
    const float* x     = (const float*)d_in[0];
    const int*   eidx  = (const int*)d_in[1];
    const float* eattr = (const float*)d_in[2];
    const int*   batch = (const int*)d_in[3];
    const float* xW    = (const float*)d_in[4];
    const float* xb    = (const float*)d_in[5];
    const float* eW    = (const float*)d_in[6];
    const float* eb    = (const float*)d_in[7];
    const float* gcnW  = (const float*)d_in[8];
    const float* gcnb  = (const float*)d_in[9];
    const float* rootE = (const float*)d_in[10];
    const float* bng   = (const float*)d_in[11];
    const float* bnb   = (const float*)d_in[12];
    const float* p1W   = (const float*)d_in[13];
    const float* p1b   = (const float*)d_in[14];
    const float* p2W   = (const float*)d_in[15];
    const float* p2b   = (const float*)d_in[16];
    const float* p3W   = (const float*)d_in[17];
    const float* p3b   = (const float*)d_in[18];
    float* out = (float*)d_out;

    const int* row = eidx;
    const int* col = eidx + NE;

    const size_t HSZ = (size_t)NN * EMB;            // 25.6M elements
    const int NWB = 5*EMB*EMB;                      // 327680

    // ---- ws layout ----
    char* p = (char*)d_ws;
    u16* t   = (u16*)p;            p += HSZ*2;      // pre-BN state
    u16* hx  = (u16*)p;            p += HSZ*2;      // GEMM output
    u16* Wb  = (u16*)p;            p += (size_t)NWB*2;
    float* eWt = (float*)p;        p += 2560*4;
    // zeroed accumulator region
    char* zbase = p;
    int* rcnt   = (int*)p;         p += (size_t)NN*4;
    int* ccnt   = (int*)p;         p += (size_t)NN*4;
    int* fill   = (int*)p;         p += (size_t)NN*4;
    float* stats= (float*)p;       p += (size_t)NLAYERS*512*4;
    float* psum = (float*)p;       p += (size_t)NG*EMB*4;
    float* pcnt = (float*)p;       p += (size_t)NG*4;
    size_t zbytes = (size_t)(p - zbase);
    float* dinv = (float*)p;       p += (size_t)NN*4;
    float* invdg= (float*)p;       p += (size_t)NN*4;
    float* bnscA= (float*)p;       p += (size_t)NLAYERS*512*4;
    int* coff   = (int*)p;         p += (size_t)(NN+1)*4;
    int* bsum   = (int*)p;         p += 512*4;
    int* bbase  = (int*)p;         p += 512*4;
    int* erow   = (int*)p;         p += (size_t)NE*4;
    float* enorm= (float*)p;       p += (size_t)NE*4;
    u16* eab    = (u16*)p;         p += (size_t)NE*16*2;
    u16* gbf    = (u16*)p;         p += (size_t)NG*EMB*2;
    u16* h1b    = (u16*)p;         p += (size_t)NG*128*2;
    u16* h2b    = (u16*)p;         p += (size_t)NG*128*2;
    u16* Wh1    = (u16*)p;         p += (size_t)128*256*2;
    u16* Wh2    = (u16*)p;         p += (size_t)128*128*2;
    size_t NEED = (size_t)(p - (char*)d_ws);
    if (ws_size < NEED) return;    // fail absmax cleanly instead of faulting

    hipMemsetAsync(zbase, 0, zbytes, stream);

    const int NBS = (NN + 255)/256;

    embed_x<<<NN/XNB, 256, 0, stream>>>(x, xW, xb, t);
    wconv<<<(NWB+255)/256, 256, 0, stream>>>(gcnW, Wb, NWB);
    wconv<<<(128*256+255)/256, 256, 0, stream>>>(p1W, Wh1, 128*256);
    wconv<<<(128*128+255)/256, 256, 0, stream>>>(p2W, Wh2, 128*128);
    ewt_kernel<<<10, 256, 0, stream>>>(eW, eWt);
    hist_kernel<<<(NE+255)/256, 256, 0, stream>>>(row, col, rcnt, ccnt, NE);
    deg_fin<<<NBS, 256, 0, stream>>>(rcnt, dinv, invdg, NN);
    scan1<<<NBS, 256, 0, stream>>>(ccnt, bsum, NN);
    scan2<<<1, 512, 0, stream>>>(bsum, bbase, coff, NBS);
    scan3<<<NBS, 256, 0, stream>>>(ccnt, bbase, coff, NN);
    csr_fill<<<(NE+255)/256, 256, 0, stream>>>(row, col, eattr, coff, dinv, fill,
                                               erow, enorm, eab, NE);

    for (int l = 0; l < NLAYERS; ++l) {
        const u16*   Wl = Wb + (size_t)l*EMB*EMB;
        const float* bl = gcnb + (size_t)l*EMB;
        const float* rl = rootE + (size_t)l*EMB;
        const float* scPrev = bnscA + (size_t)(l > 0 ? l-1 : 0)*512;
        int doBN = (l > 0) ? 1 : 0;
        gemm_mfma<<<(NN+127)/128, 512, 0, stream>>>(t, Wl, bl, scPrev, doBN, hx, NN);
        gather_combine<<<1536, 256, 0, stream>>>(erow, enorm, eab, coff, eWt, eb,
                hx, rl, invdg, scPrev, doBN, t, stats + l*512, NN);
        bn_finalize<<<1, 256, 0, stream>>>(stats + l*512, bng + (size_t)l*EMB,
                                           bnb + (size_t)l*EMB, bnscA + (size_t)l*512, NN);
    }

    pool_kernel<<<NBS, 256, 0, stream>>>(t, batch, bnscA + (size_t)(NLAYERS-1)*512,
                                         psum, pcnt, NN);
    pool2g<<<(NG*128+255)/256, 256, 0, stream>>>(psum, pcnt, gbf);
    gemm_head<<<NG/128, 256, 0, stream>>>(gbf, Wh1, p1b, h1b, NG, 256);
    gemm_head<<<NG/128, 256, 0, stream>>>(h1b, Wh2, p2b, h2b, NG, 128);
    head_final<<<(NG*16+255)/256, 256, 0, stream>>>(h2b, p3W, p3b, out, NG);
}